// Round 12
// baseline (479.776 us; speedup 1.0000x reference)
//
#include <hip/hip_runtime.h>
#include <hip/hip_bf16.h>
#include <math.h>

// Problem dims
#define B_   32
#define NO_  100
#define NE_  600
#define NK_  1000
#define KE_  1000
#define L_   8
#define R_   8
#define H_   512
#define IMG_ 2048
#define LOC_ 5
#define EMB_ 300
#define MID_ 512
#define C_   3000
#define PAD_ 1

#define NN_  (NO_ + NK_)   // 1100 node keys
#define NEK_ (NE_ + KE_)   // 1600 edge keys

typedef __attribute__((ext_vector_type(8))) short bf16x8;
typedef __attribute__((ext_vector_type(4))) float f32x4;

__device__ __forceinline__ float4 ldf4(const float* p) { return *(const float4*)p; }

__device__ __forceinline__ float bf2f(short s) {
    unsigned u = ((unsigned)(unsigned short)s) << 16;
    float f; __builtin_memcpy(&f, &u, 4); return f;
}
__device__ __forceinline__ short f2bf(float f) {
    unsigned u; __builtin_memcpy(&u, &f, 4);
    u = (u + 0x7fffu + ((u >> 16) & 1u)) >> 16;   // round-nearest-even
    return (short)u;
}

// Tiled ("Wp-format") element offset: [panel=row/128][ks=k/32][kg=(k/8)&3][r=row%128][j=k%8]
__device__ __forceinline__ long tiled_off(int row, int k, int KSa) {
    return ((((long)(row >> 7) * KSa + (k >> 5)) * 4 + ((k >> 3) & 3)) << 10)
           + ((long)(row & 127) << 3) + (k & 7);
}

// Direct global->LDS 16B/lane. LDS dest wave-uniform base (+lane*16 by HW).
__device__ __forceinline__ void gload16(const void* g, void* l) {
    __builtin_amdgcn_global_load_lds(
        (__attribute__((address_space(1))) void*)(g),
        (__attribute__((address_space(3))) void*)(l), 16, 0, 0);
}

// ---------------------------------------------------------------------------
// W_prep: f32 W[K][512] -> bf16 tiles [NB=4][KS][4 kg][128 nl][8 j]
__global__ __launch_bounds__(256) void wprep_kernel(
    const float* __restrict__ W, short* __restrict__ Wp, int K, int KS)
{
    int idx = blockIdx.x * 256 + threadIdx.x;
    int total = 4 * KS * 4 * 128;
    if (idx >= total) return;
    int nl = idx & 127;
    int kg = (idx >> 7) & 3;
    int t  = idx >> 9;            // nb*KS + ks
    int ks = t % KS;
    int nb = t / KS;
    int n = nb * 128 + nl;
    short o[8];
#pragma unroll
    for (int j = 0; j < 8; ++j) {
        int k = ks * 32 + kg * 8 + j;
        o[j] = (k < K) ? f2bf(W[(long)k * H_ + n]) : (short)0;
    }
    *(uint4*)&Wp[(long)idx * 8] = *(uint4*)o;
}

// f32 -> bf16 elementwise (embed)
__global__ __launch_bounds__(256) void cvt_bf16_kernel(
    const float* __restrict__ src, short* __restrict__ dst, long n)
{
    long i = ((long)blockIdx.x * 256 + threadIdx.x) * 8;
    if (i >= n) return;
    float4 a = ldf4(src + i), b = ldf4(src + i + 4);
    short o[8] = { f2bf(a.x), f2bf(a.y), f2bf(a.z), f2bf(a.w),
                   f2bf(b.x), f2bf(b.y), f2bf(b.z), f2bf(b.w) };
    *(uint4*)&dst[i] = *(uint4*)o;
}

// f32 row-major [rows][K] -> bf16 tiled (A-operand format)
__global__ __launch_bounds__(256) void cvt_tiled_kernel(
    const float* __restrict__ src, short* __restrict__ dst, int K, long ngroups)
{
    long g = (long)blockIdx.x * 256 + threadIdx.x;
    if (g >= ngroups) return;
    int perRow = K >> 3;
    int row = (int)(g / perRow);
    int k   = (int)(g - (long)row * perRow) * 8;
    const float* p = src + (long)row * K + k;
    float4 a = ldf4(p), b = ldf4(p + 4);
    short o[8] = { f2bf(a.x), f2bf(a.y), f2bf(a.z), f2bf(a.w),
                   f2bf(b.x), f2bf(b.y), f2bf(b.z), f2bf(b.w) };
    *(uint4*)&dst[tiled_off(row, k, K >> 5)] = *(uint4*)o;
}

// ---------------------------------------------------------------------------
// Pool: masked mean of bf16 embeddings, two token sources split at `split`.
// Writes pooled TILED (K=320, KSa=10), zeros past EMB; mask for rows < split.
__global__ __launch_bounds__(256) void pool_kernel(
    const int* __restrict__ tokA, const int* __restrict__ tokB, int split,
    int tok_stride, int tok_off, const short* __restrict__ embed_bf,
    short* __restrict__ pooled, float* __restrict__ maskout, int nrows)
{
    __shared__ int   toks[32][8];
    __shared__ float rinv[32];
    int tid = threadIdx.x, base = blockIdx.x * 32;
    const int* tokens; int local;
    if (base < split) { tokens = tokA; local = base; }
    else              { tokens = tokB; local = base - split; }
    {
        int r = tid >> 3, t = tid & 7;
        int i = base + r;
        toks[r][t] = (i < nrows) ? tokens[tok_off + (long)(local + r) * tok_stride + t] : PAD_;
    }
    __syncthreads();
    if (tid < 32) {
        int c = 0;
#pragma unroll
        for (int t = 0; t < 8; ++t) c += (toks[tid][t] != PAD_);
        rinv[tid] = 1.0f / fmaxf((float)c, 1.0f);
        int i = base + tid;
        if (maskout && i < split && i < nrows) maskout[i] = (c > 0) ? 1.0f : 0.0f;
    }
    __syncthreads();

    for (int task = tid; task < 32 * 40; task += 256) {
        int r = task / 40, kg = task - r * 40;
        float s[8] = {0.f,0.f,0.f,0.f,0.f,0.f,0.f,0.f};
        if (kg < 38) {
#pragma unroll
            for (int t = 0; t < 8; ++t) {
                int tok = toks[r][t];
                if (tok != PAD_) {
                    bf16x8 e = *(const bf16x8*)&embed_bf[(long)tok * EMB_ + kg * 8];
#pragma unroll
                    for (int j = 0; j < 8; ++j) s[j] += bf2f(e[j]);
                }
            }
        }
        float iv = rinv[r];
        short o[8];
#pragma unroll
        for (int j = 0; j < 8; ++j) {
            float v = s[j] * iv;
            if (kg == 37 && j >= 4) v = 0.f;
            o[j] = f2bf(v);
        }
        *(uint4*)&pooled[tiled_off(base + r, kg * 8, 10)] = *(uint4*)o;
    }
}

// ---------------------------------------------------------------------------
// Keys GEMM: tiled pooled @ W_lang -> tanh(+bias) -> TILED keys.
// 128x128 tile, 4 waves, BK=64 DOUBLE-buffered; counted vmcnt(8) + raw
// s_barrier -> prefetch loads stay in flight across the barrier.
template<int DUAL>
__global__ __launch_bounds__(256) void keys_gemm_kernel(
    const short* __restrict__ Atl, const short* __restrict__ Wp,
    const float* __restrict__ bias,
    short* __restrict__ node_tl, short* __restrict__ edge_tl,
    float* __restrict__ outf, int nrows)
{
    const int NCH = 5;                         // K=320 in chunks of 64
    __shared__ __align__(16) short As[2 * 8192];
    __shared__ __align__(16) short Bs[2 * 8192];
    int tid = threadIdx.x;
    int m0 = blockIdx.x * 128, nb = blockIdx.y, n0 = nb * 128;
    int w = tid >> 6, l = tid & 63, wr = w >> 1, wc = w & 1;
    const short* wslab = Wp + (long)nb * (NCH * 2) * 4096;
    const short* aslab0 = Atl + (long)blockIdx.x * (NCH * 2) * 4096;

    auto stage = [&](int buf, int t) {
        const short* aslab = aslab0 + (long)(t * 2) * 4096;
        const short* bslab = wslab + (long)(t * 2) * 4096;
        short* Ad = As + buf * 8192;
        short* Bd = Bs + buf * 8192;
#pragma unroll
        for (int j = 0; j < 4; ++j) {
            int c = w * 4 + j;
            gload16(aslab + c * 512 + l * 8, Ad + c * 512);
            gload16(bslab + c * 512 + l * 8, Bd + c * 512);
        }
    };

    f32x4 acc[4][4];
#pragma unroll
    for (int m = 0; m < 4; ++m)
#pragma unroll
        for (int n = 0; n < 4; ++n)
#pragma unroll
            for (int k = 0; k < 4; ++k) acc[m][n][k] = 0.f;

    int kg = l >> 4, li = l & 15;
    stage(0, 0);
    for (int t = 0; t < NCH; ++t) {
        int cur = t & 1;
        if (t + 1 < NCH) {
            stage(cur ^ 1, t + 1);                         // 8 new loads in flight
            asm volatile("s_waitcnt vmcnt(8)" ::: "memory");  // prev chunk done
        } else {
            asm volatile("s_waitcnt vmcnt(0)" ::: "memory");
        }
        __builtin_amdgcn_s_barrier();
        const short* Ab = As + cur * 8192;
        const short* Bb = Bs + cur * 8192;
#pragma unroll
        for (int s = 0; s < 2; ++s) {
            bf16x8 af[4], bfr[4];
#pragma unroll
            for (int m = 0; m < 4; ++m)
                af[m] = *(const bf16x8*)&Ab[(s * 4 + kg) * 1024 + (wr * 64 + m * 16 + li) * 8];
#pragma unroll
            for (int n = 0; n < 4; ++n)
                bfr[n] = *(const bf16x8*)&Bb[(s * 4 + kg) * 1024 + (wc * 64 + n * 16 + li) * 8];
#pragma unroll
            for (int m = 0; m < 4; ++m)
#pragma unroll
                for (int n = 0; n < 4; ++n)
                    acc[m][n] = __builtin_amdgcn_mfma_f32_16x16x32_bf16(af[m], bfr[n], acc[m][n], 0, 0, 0);
        }
        asm volatile("" ::: "memory");
        __builtin_amdgcn_s_barrier();                      // reads done before overwrite
    }

    int jrow4 = (l >> 4) * 4;
    float bv[4];
#pragma unroll
    for (int n = 0; n < 4; ++n) bv[n] = bias[n0 + wc * 64 + n * 16 + li];
#pragma unroll
    for (int m = 0; m < 4; ++m)
#pragma unroll
        for (int j = 0; j < 4; ++j) {
            int i = m0 + wr * 64 + m * 16 + jrow4 + j;
            if (i >= nrows) continue;
#pragma unroll
            for (int n = 0; n < 4; ++n) {
                int col = n0 + wc * 64 + n * 16 + li;
                float val = tanhf(acc[m][n][j] + bv[n]);
                if (DUAL) {
                    if (i < B_ * NK_) {
                        int b = i / NK_, k = i - b * NK_;
                        long gr = (long)b * NN_ + NO_ + k;
                        node_tl[tiled_off((int)gr, col, 16)] = f2bf(val);
                    } else {
                        int i2 = i - B_ * NK_;
                        int b = i2 / KE_, k = i2 - b * KE_;
                        long gr = (long)b * NEK_ + NE_ + k;
                        edge_tl[tiled_off((int)gr, col, 16)] = f2bf(val);
                    }
                } else {
                    outf[(long)i * H_ + col] = val;
                }
            }
        }
}

// ---------------------------------------------------------------------------
// MFMA GEMM: 128x128 tile, BK=64 DOUBLE-buffered, counted vmcnt(8) + raw
// s_barrier pipeline; grid (panels, 4).
// AV: 3 = tiled A (contiguous slab copy), 2 = gathered img_f rows (K=1024).
// EP: 0 img_node, 1 img_edge (tiled out), 2 score partials.
template<int AV, int EP, int NCH>
__global__ __launch_bounds__(256) void mfma_gemm_kernel(
    const short* __restrict__ A, const short* __restrict__ Wp,
    const int* __restrict__ id1, const int* __restrict__ id2,
    const short* __restrict__ Agather,
    const float* __restrict__ bias, const float* __restrict__ bias2,
    const float* __restrict__ loc, const float* __restrict__ Wloc,
    const float* __restrict__ qp, const float* __restrict__ vvec,
    short* __restrict__ out0, short* __restrict__ out1,
    float* __restrict__ sout, int Nrows, int Mtot)
{
    __shared__ __align__(16) short As[2 * 8192];
    __shared__ __align__(16) short Bs[2 * 8192];
    int tid = threadIdx.x;
    int m0 = blockIdx.x * 128, nb = blockIdx.y, n0 = nb * 128;
    int w = tid >> 6, l = tid & 63, wr = w >> 1, wc = w & 1;

    int r1[2], r2[2];                          // AV=2 gathered rows (per lane)
    if (AV == 2) {
#pragma unroll
        for (int i = 0; i < 2; ++i) {
            int row = m0 + i * 64 + l;
            int b = row / NE_;
            r1[i] = b * NO_ + id1[row];
            r2[i] = b * NO_ + id2[row];
        }
    }
    const short* wslab = Wp + (long)nb * (NCH * 2) * 4096;
    const short* aslab0 = (AV == 3) ? A + (long)blockIdx.x * (NCH * 2) * 4096 : nullptr;

    auto stage = [&](int buf, int t) {
        const short* bslab = wslab + (long)(t * 2) * 4096;
        short* Ad = As + buf * 8192;
        short* Bd = Bs + buf * 8192;
#pragma unroll
        for (int j = 0; j < 4; ++j) {
            int c = w * 4 + j;
            if (AV == 3) {
                gload16(aslab0 + (long)(t * 2) * 4096 + c * 512 + l * 8, Ad + c * 512);
            } else {
                int g = c >> 1, h2 = c & 1;
                int kk = t * 64 + g * 8;
                int row = (kk < 512) ? r1[h2] : r2[h2];
                gload16(Agather + (long)row * 512 + (kk & 511), Ad + c * 512);
            }
            gload16(bslab + c * 512 + l * 8, Bd + c * 512);
        }
    };

    f32x4 acc[4][4];
#pragma unroll
    for (int m = 0; m < 4; ++m)
#pragma unroll
        for (int n = 0; n < 4; ++n)
#pragma unroll
            for (int k = 0; k < 4; ++k) acc[m][n][k] = 0.f;

    int kg = l >> 4, li = l & 15;
    stage(0, 0);
    for (int t = 0; t < NCH; ++t) {
        int cur = t & 1;
        if (t + 1 < NCH) {
            stage(cur ^ 1, t + 1);
            asm volatile("s_waitcnt vmcnt(8)" ::: "memory");
        } else {
            asm volatile("s_waitcnt vmcnt(0)" ::: "memory");
        }
        __builtin_amdgcn_s_barrier();
        const short* Ab = As + cur * 8192;
        const short* Bb = Bs + cur * 8192;
#pragma unroll
        for (int s = 0; s < 2; ++s) {
            bf16x8 af[4], bfr[4];
#pragma unroll
            for (int m = 0; m < 4; ++m)
                af[m] = *(const bf16x8*)&Ab[(s * 4 + kg) * 1024 + (wr * 64 + m * 16 + li) * 8];
#pragma unroll
            for (int n = 0; n < 4; ++n)
                bfr[n] = *(const bf16x8*)&Bb[(s * 4 + kg) * 1024 + (wc * 64 + n * 16 + li) * 8];
#pragma unroll
            for (int m = 0; m < 4; ++m)
#pragma unroll
                for (int n = 0; n < 4; ++n)
                    acc[m][n] = __builtin_amdgcn_mfma_f32_16x16x32_bf16(af[m], bfr[n], acc[m][n], 0, 0, 0);
        }
        asm volatile("" ::: "memory");
        __builtin_amdgcn_s_barrier();
    }

    int jrow4 = (l >> 4) * 4;
    if (EP == 0) {                             // img_node
        float bi[4], bl[4], wl[4][5];
#pragma unroll
        for (int n = 0; n < 4; ++n) {
            int col = n0 + wc * 64 + n * 16 + li;
            bi[n] = bias[col]; bl[n] = bias2[col];
#pragma unroll
            for (int j5 = 0; j5 < 5; ++j5) wl[n][j5] = Wloc[j5 * H_ + col];
        }
#pragma unroll
        for (int m = 0; m < 4; ++m)
#pragma unroll
            for (int j = 0; j < 4; ++j) {
                int row = m0 + wr * 64 + m * 16 + jrow4 + j;
                int b = row / NO_, o = row - b * NO_;
                float lv[5];
#pragma unroll
                for (int j5 = 0; j5 < 5; ++j5) lv[j5] = loc[(long)row * 5 + j5];
                long gr = (long)b * NN_ + o;
#pragma unroll
                for (int n = 0; n < 4; ++n) {
                    int col = n0 + wc * 64 + n * 16 + li;
                    float val = acc[m][n][j] + bi[n];
                    out0[(long)row * H_ + col] = f2bf(val);          // img_f row-major
                    float nk = val + bl[n];
#pragma unroll
                    for (int j5 = 0; j5 < 5; ++j5) nk = fmaf(lv[j5], wl[n][j5], nk);
                    out1[tiled_off((int)gr, col, 16)] = f2bf(nk);    // node keys tiled
                }
            }
    } else if (EP == 1) {                      // img_edge
        float bi[4];
#pragma unroll
        for (int n = 0; n < 4; ++n) bi[n] = bias[n0 + wc * 64 + n * 16 + li];
#pragma unroll
        for (int m = 0; m < 4; ++m)
#pragma unroll
            for (int j = 0; j < 4; ++j) {
                int row = m0 + wr * 64 + m * 16 + jrow4 + j;
                int b = row / NE_, e = row - b * NE_;
                long gr = (long)b * NEK_ + e;
#pragma unroll
                for (int n = 0; n < 4; ++n) {
                    int col = n0 + wc * 64 + n * 16 + li;
                    out0[tiled_off((int)gr, col, 16)] = f2bf(acc[m][n][j] + bi[n]);
                }
            }
    } else {                                   // score partials
        float vv[4];
        int cols[4];
#pragma unroll
        for (int n = 0; n < 4; ++n) {
            cols[n] = n0 + wc * 64 + n * 16 + li;
            vv[n] = vvec[cols[n]];
        }
        int slot = nb * 2 + wc;
#pragma unroll
        for (int m = 0; m < 4; ++m)
#pragma unroll
            for (int j = 0; j < 4; ++j) {
                int row = m0 + wr * 64 + m * 16 + jrow4 + j;
                int b = row / Nrows;
                const float* qpb = qp + (long)b * H_;
                float p = 0.f;
#pragma unroll
                for (int n = 0; n < 4; ++n)
                    p += tanhf(qpb[cols[n]] + acc[m][n][j]) * vv[n];
                p += __shfl_xor(p, 1); p += __shfl_xor(p, 2);
                p += __shfl_xor(p, 4); p += __shfl_xor(p, 8);
                if (li == 0) sout[(long)slot * Mtot + row] = p;
            }
    }
}

// ---------------------------------------------------------------------------
// Softmax weights: combine 8 deterministic partials, mask, normalize.
__global__ __launch_bounds__(256) void softmax_w_kernel(
    const float* __restrict__ sp_n, const float* __restrict__ sp_e,
    const float* __restrict__ maskbuf, float* __restrict__ wn, float* __restrict__ we)
{
    __shared__ float sw[NEK_];
    __shared__ float red[256];
    int b = blockIdx.x, tid = threadIdx.x, set = blockIdx.y;
    const float* sp = set ? sp_e : sp_n;
    float* wout = set ? we : wn;
    int N = set ? NEK_ : NN_;
    long Mtot = set ? (long)B_ * NEK_ : (long)B_ * NN_;

    float lmax = -3.0e38f;
    for (int n = tid; n < N; n += 256) {
        long row = (long)b * N + n;
        float x = 0.f;
#pragma unroll
        for (int s = 0; s < 8; ++s) x += sp[(long)s * Mtot + row];
        if (!set && n >= NO_ && maskbuf[(long)b * NK_ + (n - NO_)] == 0.f) x = -1e30f;
        sw[n] = x;
        lmax = fmaxf(lmax, x);
    }
    red[tid] = lmax; __syncthreads();
    for (int st = 128; st > 0; st >>= 1) {
        if (tid < st) red[tid] = fmaxf(red[tid], red[tid + st]);
        __syncthreads();
    }
    float mx = red[0]; __syncthreads();

    float lsum = 0.f;
    for (int n = tid; n < N; n += 256) {
        float e = expf(sw[n] - mx);
        sw[n] = e;
        lsum += e;
    }
    red[tid] = lsum; __syncthreads();
    for (int st = 128; st > 0; st >>= 1) {
        if (tid < st) red[tid] += red[tid + st];
        __syncthreads();
    }
    float invZ = 1.0f / red[0];
    __syncthreads();
    for (int n = tid; n < N; n += 256)
        wout[(long)b * N + n] = sw[n] * invZ;
}

// ---------------------------------------------------------------------------
// Weighted key sum over TILED keys, split over n: grid (B, SP).
template<int SP>
__global__ __launch_bounds__(256) void wsum_kernel(
    const float* __restrict__ w, const short* __restrict__ keys_tl,
    float* __restrict__ partial, int N)
{
    __shared__ float red[4][512];
    int b = blockIdx.x, sp = blockIdx.y, tid = threadIdx.x;
    int c8 = (tid & 63) * 8, rsub = tid >> 6;
    int per = (N + SP - 1) / SP;
    int n0 = sp * per, n1 = min(n0 + per, N);
    float acc[8] = {0.f,0.f,0.f,0.f,0.f,0.f,0.f,0.f};
    for (int n = n0 + rsub; n < n1; n += 4) {
        float wv = w[(long)b * N + n];
        bf16x8 k = *(const bf16x8*)&keys_tl[tiled_off(b * N + n, c8, 16)];
#pragma unroll
        for (int j = 0; j < 8; ++j) acc[j] = fmaf(wv, bf2f(k[j]), acc[j]);
    }
    *(float4*)&red[rsub][c8]     = *(float4*)acc;
    *(float4*)&red[rsub][c8 + 4] = *(float4*)(acc + 4);
    __syncthreads();
    if (rsub == 0) {
        float o[8];
#pragma unroll
        for (int j = 0; j < 8; ++j)
            o[j] = red[0][c8 + j] + red[1][c8 + j] + red[2][c8 + j] + red[3][c8 + j];
        float* op = &partial[((long)sp * B_ + b) * H_ + c8];
        *(float4*)op       = *(float4*)o;
        *(float4*)(op + 4) = *(float4*)(o + 4);
    }
}

// fin = sum over 16 node partials + 16 edge partials. grid (B*H/256).
__global__ __launch_bounds__(256) void fin_reduce_kernel(
    const float* __restrict__ pn, const float* __restrict__ pe, float* __restrict__ fin)
{
    int i = blockIdx.x * 256 + threadIdx.x;
    float s = 0.f;
#pragma unroll
    for (int sp = 0; sp < 16; ++sp)
        s += pn[(long)sp * B_ * H_ + i] + pe[(long)sp * B_ * H_ + i];
    fin[i] = s;
}

// ---------------------------------------------------------------------------
// K-split matvec over all 32 batch rows; deterministic partials.
template<int E, int CHUNK>
__global__ __launch_bounds__(256) void kmatvec_kernel(
    const float* __restrict__ in, const float* __restrict__ Wa,
    const float* __restrict__ Wb, float* __restrict__ pa,
    float* __restrict__ pb, int C)
{
    __shared__ float ins[32 * CHUNK];
    int tid = threadIdx.x;
    int ks = blockIdx.y, k0 = ks * CHUNK;
    const float* W   = (blockIdx.z == 0) ? Wa : Wb;
    float* partial   = (blockIdx.z == 0) ? pa : pb;
    for (int t = tid; t < 32 * CHUNK; t += 256) {
        int b = t / CHUNK, k = t - b * CHUNK;
        ins[t] = in[(long)b * E + k0 + k];
    }
    __syncthreads();
    int c = blockIdx.x * 256 + tid;
    if (c >= C) return;
    float acc[32];
#pragma unroll
    for (int b = 0; b < 32; ++b) acc[b] = 0.f;
    for (int k = 0; k < CHUNK; ++k) {
        float wv = W[(long)(k0 + k) * C + c];
#pragma unroll
        for (int b = 0; b < 32; ++b)
            acc[b] = fmaf(ins[b * CHUNK + k], wv, acc[b]);
    }
#pragma unroll
    for (int b = 0; b < 32; ++b)
        partial[((long)ks * 32 + b) * C + c] = acc[b];
}

template<int ACT, int KS>
__global__ __launch_bounds__(256) void kreduce_kernel(
    const float* __restrict__ pa, const float* __restrict__ pb,
    const float* __restrict__ biasa, const float* __restrict__ biasb,
    float* __restrict__ oa, float* __restrict__ ob, int C)
{
    int set = blockIdx.y;
    const float* p    = set ? pb : pa;
    const float* bias = set ? biasb : biasa;
    float* o          = set ? ob : oa;
    long i = (long)blockIdx.x * 256 + threadIdx.x;
    if (i >= 32L * C) return;
    int c = (int)(i % C);
    float s = bias ? bias[c] : 0.f;
#pragma unroll
    for (int ks = 0; ks < KS; ++ks) s += p[(long)ks * 32 * C + i];
    o[i] = (ACT == 1) ? tanhf(s) : s;
}

// ---------------------------------------------------------------------------
extern "C" void kernel_launch(void* const* d_in, const int* in_sizes, int n_in,
                              void* d_out, int out_size, void* d_ws, size_t ws_size,
                              hipStream_t stream)
{
    (void)in_sizes; (void)n_in; (void)out_size; (void)ws_size;

    const float* img_feat  = (const float*)d_in[0];
    const float* img_loc   = (const float*)d_in[1];
    const int*   id1       = (const int*)d_in[2];
    const int*   id2       = (const int*)d_in[3];
    const int*   kg_entity = (const int*)d_in[4];
    const int*   kg_edge   = (const int*)d_in[7];
    const int*   r_nodes   = (const int*)d_in[8];
    const float* embed     = (const float*)d_in[11];
    const float* W_lang    = (const float*)d_in[12];
    const float* b_lang    = (const float*)d_in[13];
    const float* W_img     = (const float*)d_in[14];
    const float* b_img     = (const float*)d_in[15];
    const float* W_loc     = (const float*)d_in[16];
    const float* b_loc     = (const float*)d_in[17];
    const float* W_rel     = (const float*)d_in[18];
    const float* b_rel     = (const float*)d_in[19];
    const float* Wq_n      = (const float*)d_in[20];
    const float* Wk_n      = (const float*)d_in[21];
    const float* v_n       = (const float*)d_in[22];
    const float* Wq_e      = (const float*)d_in[23];
    const float* Wk_e      = (const float*)d_in[24];
    const float* v_e       = (const float*)d_in[25];
    const float* W1        = (const float*)d_in[26];
    const float* b1        = (const float*)d_in[27];
    const float* W2        = (const float*)d_in[28];
    const float* b2        = (const float*)d_in[29];
    float* out = (float*)d_out;

    char* ws = (char*)d_ws;
    size_t off = 0;
    auto allocS = [&](size_t n) { short* p = (short*)(ws + off); off += ((n * 2 + 255) & ~255ULL); return p; };
    auto allocF = [&](size_t n) { float* p = (float*)(ws + off); off += ((n * 4 + 255) & ~255ULL); return p; };

    short* img_feat_tl = allocS((size_t)B_ * NO_ * IMG_);      // 13 MB (tiled)
    short* embed_bf    = allocS((size_t)10000 * EMB_ + 16);    // 6 MB
    short* Wp_img      = allocS((size_t)4 * 64 * 4096);
    short* Wp_rel      = allocS((size_t)4 * 32 * 4096);
    short* Wp_kn       = allocS((size_t)4 * 16 * 4096);
    short* Wp_ke       = allocS((size_t)4 * 16 * 4096);
    short* Wp_lang     = allocS((size_t)4 * 10 * 4096);
    short* img_f_bf    = allocS((size_t)B_ * NO_ * H_);        // row-major (gather src)
    short* node_tl     = allocS((size_t)B_ * NN_ * H_);        // 36 MB tiled keys
    short* edge_tl     = allocS((size_t)B_ * NEK_ * H_);       // 52 MB tiled keys
    short* pooled      = allocS((size_t)2 * B_ * NK_ * 320);   // 41 MB tiled
    short* pooled_r    = allocS((size_t)10 * 4096);            // 1 panel tiled
    float* rfeat   = allocF((size_t)B_ * H_);
    float* qp_n    = allocF((size_t)B_ * H_);
    float* qp_e    = allocF((size_t)B_ * H_);
    float* mask_kg = allocF((size_t)B_ * NK_);
    float* sp_n    = allocF((size_t)8 * B_ * NN_);             // score partials
    float* sp_e    = allocF((size_t)8 * B_ * NEK_);
    float* wn      = allocF((size_t)B_ * NN_);
    float* we      = allocF((size_t)B_ * NEK_);
    float* pn      = allocF((size_t)16 * B_ * H_);
    float* pe      = allocF((size_t)16 * B_ * H_);
    float* fin     = allocF((size_t)B_ * H_);
    float* hid     = allocF((size_t)B_ * H_);
    float* pq_n    = allocF((size_t)16 * B_ * MID_);
    float* pq_e    = allocF((size_t)16 * B_ * MID_);
    float* ph1     = allocF((size_t)16 * B_ * MID_);
    float* ph2     = allocF((size_t)16 * B_ * C_);

    // --- weight prep + input conversion ---
    cvt_tiled_kernel<<<(B_ * NO_ * IMG_ / 8 + 255) / 256, 256, 0, stream>>>(
        img_feat, img_feat_tl, IMG_, (long)B_ * NO_ * IMG_ / 8);
    cvt_bf16_kernel<<<(10000 * EMB_ / 8 + 255) / 256, 256, 0, stream>>>(
        embed, embed_bf, (long)10000 * EMB_);
    wprep_kernel<<<512, 256, 0, stream>>>(W_img,  Wp_img,  IMG_, 64);
    wprep_kernel<<<256, 256, 0, stream>>>(W_rel,  Wp_rel,  1024, 32);
    wprep_kernel<<<128, 256, 0, stream>>>(Wk_n,   Wp_kn,   512,  16);
    wprep_kernel<<<128, 256, 0, stream>>>(Wk_e,   Wp_ke,   512,  16);
    wprep_kernel<<< 80, 256, 0, stream>>>(W_lang, Wp_lang, EMB_, 10);

    // --- pooled embeddings (merged node+edge gather, tiled out) ---
    pool_kernel<<<2 * B_ * NK_ / 32, 256, 0, stream>>>(
        kg_entity, kg_edge, B_ * NK_, L_, 0, embed_bf, pooled, mask_kg, 2 * B_ * NK_);
    pool_kernel<<<1, 256, 0, stream>>>(
        r_nodes, nullptr, 1 << 30, R_ * L_, (R_ - 1) * L_, embed_bf, pooled_r,
        nullptr, B_);

    // --- lang projections (A = tiled slabs; keys written tiled) ---
    keys_gemm_kernel<1><<<dim3(2 * B_ * NK_ / 128, 4), 256, 0, stream>>>(
        pooled, Wp_lang, b_lang, node_tl, edge_tl, nullptr, 2 * B_ * NK_);
    keys_gemm_kernel<0><<<dim3(1, 4), 256, 0, stream>>>(
        pooled_r, Wp_lang, b_lang, nullptr, nullptr, rfeat, B_);

    // --- qp for root program node (fused pair, K-split) ---
    kmatvec_kernel<H_, 32><<<dim3(2, 16, 2), 256, 0, stream>>>(
        rfeat, Wq_n, Wq_e, pq_n, pq_e, MID_);
    kreduce_kernel<0, 16><<<dim3(B_ * MID_ / 256, 2), 256, 0, stream>>>(
        pq_n, pq_e, nullptr, nullptr, qp_n, qp_e, MID_);

    // --- image branches ---
    mfma_gemm_kernel<3, 0, 32><<<dim3(B_ * NO_ / 128, 4), 256, 0, stream>>>(
        img_feat_tl, Wp_img, nullptr, nullptr, nullptr,
        b_img, b_loc, img_loc, W_loc, nullptr, nullptr,
        img_f_bf, node_tl, nullptr, 0, 0);
    mfma_gemm_kernel<2, 1, 16><<<dim3(B_ * NE_ / 128, 4), 256, 0, stream>>>(
        nullptr, Wp_rel, id1, id2, img_f_bf,
        b_rel, nullptr, nullptr, nullptr, nullptr, nullptr,
        edge_tl, nullptr, nullptr, 0, 0);

    // --- fused keys@Wk + tanh-attention score partials (A tiled) ---
    mfma_gemm_kernel<3, 2, 8><<<dim3(B_ * NN_ / 128, 4), 256, 0, stream>>>(
        node_tl, Wp_kn, nullptr, nullptr, nullptr,
        nullptr, nullptr, nullptr, nullptr, qp_n, v_n,
        nullptr, nullptr, sp_n, NN_, B_ * NN_);
    mfma_gemm_kernel<3, 2, 8><<<dim3(B_ * NEK_ / 128, 4), 256, 0, stream>>>(
        edge_tl, Wp_ke, nullptr, nullptr, nullptr,
        nullptr, nullptr, nullptr, nullptr, qp_e, v_e,
        nullptr, nullptr, sp_e, NEK_, B_ * NEK_);

    // --- softmax weights + parallel weighted sums (tiled keys) ---
    softmax_w_kernel<<<dim3(B_, 2), 256, 0, stream>>>(sp_n, sp_e, mask_kg, wn, we);
    wsum_kernel<16><<<dim3(B_, 16), 256, 0, stream>>>(wn, node_tl, pn, NN_);
    wsum_kernel<16><<<dim3(B_, 16), 256, 0, stream>>>(we, edge_tl, pe, NEK_);
    fin_reduce_kernel<<<B_ * H_ / 256, 256, 0, stream>>>(pn, pe, fin);

    // --- head: hid = tanh(fin@W1 + b1); out = hid@W2 + b2 ---
    kmatvec_kernel<H_, 32><<<dim3(2, 16, 1), 256, 0, stream>>>(
        fin, W1, W1, ph1, ph1, MID_);
    kreduce_kernel<1, 16><<<dim3(B_ * MID_ / 256, 1), 256, 0, stream>>>(
        ph1, ph1, b1, b1, hid, hid, MID_);
    kmatvec_kernel<MID_, 32><<<dim3((C_ + 255) / 256, 16, 1), 256, 0, stream>>>(
        hid, W2, W2, ph2, ph2, C_);
    kreduce_kernel<0, 16><<<dim3((B_ * C_ + 255) / 256, 1), 256, 0, stream>>>(
        ph2, ph2, b2, b2, out, out, C_);
}

// Round 13
// 450.046 us; speedup vs baseline: 1.0661x; 1.0661x over previous
//
#include <hip/hip_runtime.h>
#include <hip/hip_bf16.h>
#include <math.h>

// Problem dims
#define B_   32
#define NO_  100
#define NE_  600
#define NK_  1000
#define KE_  1000
#define L_   8
#define R_   8
#define H_   512
#define IMG_ 2048
#define LOC_ 5
#define EMB_ 300
#define MID_ 512
#define C_   3000
#define PAD_ 1

#define NN_  (NO_ + NK_)   // 1100 node keys
#define NEK_ (NE_ + KE_)   // 1600 edge keys

typedef __attribute__((ext_vector_type(8))) short bf16x8;
typedef __attribute__((ext_vector_type(4))) float f32x4;

__device__ __forceinline__ float4 ldf4(const float* p) { return *(const float4*)p; }

__device__ __forceinline__ float bf2f(short s) {
    unsigned u = ((unsigned)(unsigned short)s) << 16;
    float f; __builtin_memcpy(&f, &u, 4); return f;
}
__device__ __forceinline__ short f2bf(float f) {
    unsigned u; __builtin_memcpy(&u, &f, 4);
    u = (u + 0x7fffu + ((u >> 16) & 1u)) >> 16;   // round-nearest-even
    return (short)u;
}

// Fast tanh: 1 - 2/(1+exp(2x)). ~5 VALU ops vs libm's ~40 (range-reduced).
// Saturates correctly (exp->inf => 1, exp->0 => -1); |err| ~1e-6.
__device__ __forceinline__ float fast_tanh(float x) {
    float e = __expf(2.0f * x);
    return 1.0f - 2.0f / (e + 1.0f);
}

// Tiled ("Wp-format") element offset: [panel=row/128][ks=k/32][kg=(k/8)&3][r=row%128][j=k%8]
__device__ __forceinline__ long tiled_off(int row, int k, int KSa) {
    return ((((long)(row >> 7) * KSa + (k >> 5)) * 4 + ((k >> 3) & 3)) << 10)
           + ((long)(row & 127) << 3) + (k & 7);
}

// Direct global->LDS 16B/lane. LDS dest wave-uniform base (+lane*16 by HW).
__device__ __forceinline__ void gload16(const void* g, void* l) {
    __builtin_amdgcn_global_load_lds(
        (__attribute__((address_space(1))) void*)(g),
        (__attribute__((address_space(3))) void*)(l), 16, 0, 0);
}

// ---------------------------------------------------------------------------
// W_prep: f32 W[K][512] -> bf16 tiles [NB=4][KS][4 kg][128 nl][8 j]
__global__ __launch_bounds__(256) void wprep_kernel(
    const float* __restrict__ W, short* __restrict__ Wp, int K, int KS)
{
    int idx = blockIdx.x * 256 + threadIdx.x;
    int total = 4 * KS * 4 * 128;
    if (idx >= total) return;
    int nl = idx & 127;
    int kg = (idx >> 7) & 3;
    int t  = idx >> 9;            // nb*KS + ks
    int ks = t % KS;
    int nb = t / KS;
    int n = nb * 128 + nl;
    short o[8];
#pragma unroll
    for (int j = 0; j < 8; ++j) {
        int k = ks * 32 + kg * 8 + j;
        o[j] = (k < K) ? f2bf(W[(long)k * H_ + n]) : (short)0;
    }
    *(uint4*)&Wp[(long)idx * 8] = *(uint4*)o;
}

// f32 -> bf16 elementwise (embed)
__global__ __launch_bounds__(256) void cvt_bf16_kernel(
    const float* __restrict__ src, short* __restrict__ dst, long n)
{
    long i = ((long)blockIdx.x * 256 + threadIdx.x) * 8;
    if (i >= n) return;
    float4 a = ldf4(src + i), b = ldf4(src + i + 4);
    short o[8] = { f2bf(a.x), f2bf(a.y), f2bf(a.z), f2bf(a.w),
                   f2bf(b.x), f2bf(b.y), f2bf(b.z), f2bf(b.w) };
    *(uint4*)&dst[i] = *(uint4*)o;
}

// f32 row-major [rows][K] -> bf16 tiled (A-operand format)
__global__ __launch_bounds__(256) void cvt_tiled_kernel(
    const float* __restrict__ src, short* __restrict__ dst, int K, long ngroups)
{
    long g = (long)blockIdx.x * 256 + threadIdx.x;
    if (g >= ngroups) return;
    int perRow = K >> 3;
    int row = (int)(g / perRow);
    int k   = (int)(g - (long)row * perRow) * 8;
    const float* p = src + (long)row * K + k;
    float4 a = ldf4(p), b = ldf4(p + 4);
    short o[8] = { f2bf(a.x), f2bf(a.y), f2bf(a.z), f2bf(a.w),
                   f2bf(b.x), f2bf(b.y), f2bf(b.z), f2bf(b.w) };
    *(uint4*)&dst[tiled_off(row, k, K >> 5)] = *(uint4*)o;
}

// ---------------------------------------------------------------------------
// Pool: masked mean of bf16 embeddings, two token sources split at `split`.
// Writes pooled TILED (K=320, KSa=10), zeros past EMB; mask for rows < split.
__global__ __launch_bounds__(256) void pool_kernel(
    const int* __restrict__ tokA, const int* __restrict__ tokB, int split,
    int tok_stride, int tok_off, const short* __restrict__ embed_bf,
    short* __restrict__ pooled, float* __restrict__ maskout, int nrows)
{
    __shared__ int   toks[32][8];
    __shared__ float rinv[32];
    int tid = threadIdx.x, base = blockIdx.x * 32;
    const int* tokens; int local;
    if (base < split) { tokens = tokA; local = base; }
    else              { tokens = tokB; local = base - split; }
    {
        int r = tid >> 3, t = tid & 7;
        int i = base + r;
        toks[r][t] = (i < nrows) ? tokens[tok_off + (long)(local + r) * tok_stride + t] : PAD_;
    }
    __syncthreads();
    if (tid < 32) {
        int c = 0;
#pragma unroll
        for (int t = 0; t < 8; ++t) c += (toks[tid][t] != PAD_);
        rinv[tid] = 1.0f / fmaxf((float)c, 1.0f);
        int i = base + tid;
        if (maskout && i < split && i < nrows) maskout[i] = (c > 0) ? 1.0f : 0.0f;
    }
    __syncthreads();

    for (int task = tid; task < 32 * 40; task += 256) {
        int r = task / 40, kg = task - r * 40;
        float s[8] = {0.f,0.f,0.f,0.f,0.f,0.f,0.f,0.f};
        if (kg < 38) {
#pragma unroll
            for (int t = 0; t < 8; ++t) {
                int tok = toks[r][t];
                if (tok != PAD_) {
                    bf16x8 e = *(const bf16x8*)&embed_bf[(long)tok * EMB_ + kg * 8];
#pragma unroll
                    for (int j = 0; j < 8; ++j) s[j] += bf2f(e[j]);
                }
            }
        }
        float iv = rinv[r];
        short o[8];
#pragma unroll
        for (int j = 0; j < 8; ++j) {
            float v = s[j] * iv;
            if (kg == 37 && j >= 4) v = 0.f;
            o[j] = f2bf(v);
        }
        *(uint4*)&pooled[tiled_off(base + r, kg * 8, 10)] = *(uint4*)o;
    }
}

// ---------------------------------------------------------------------------
// Keys GEMM: tiled pooled @ W_lang -> fast_tanh(+bias) -> TILED keys.
// 128x128 tile, 4 waves, BK=64 single-buffer; A staging = contiguous slab copy.
template<int DUAL>
__global__ __launch_bounds__(256) void keys_gemm_kernel(
    const short* __restrict__ Atl, const short* __restrict__ Wp,
    const float* __restrict__ bias,
    short* __restrict__ node_tl, short* __restrict__ edge_tl,
    float* __restrict__ outf, int nrows)
{
    const int NCH = 5;                         // K=320 in chunks of 64
    __shared__ __align__(16) short As[8192];
    __shared__ __align__(16) short Bs[8192];
    int tid = threadIdx.x;
    int m0 = blockIdx.x * 128, nb = blockIdx.y, n0 = nb * 128;
    int w = tid >> 6, l = tid & 63, wr = w >> 1, wc = w & 1;
    const short* wslab = Wp + (long)nb * (NCH * 2) * 4096;
    const short* aslab0 = Atl + (long)blockIdx.x * (NCH * 2) * 4096;

    f32x4 acc[4][4];
#pragma unroll
    for (int m = 0; m < 4; ++m)
#pragma unroll
        for (int n = 0; n < 4; ++n)
#pragma unroll
            for (int k = 0; k < 4; ++k) acc[m][n][k] = 0.f;

    int kg = l >> 4, li = l & 15;
    for (int t = 0; t < NCH; ++t) {
        const short* aslab = aslab0 + (long)(t * 2) * 4096;
        const short* bslab = wslab + (long)(t * 2) * 4096;
#pragma unroll
        for (int j = 0; j < 4; ++j) {
            int c = w * 4 + j;
            gload16(aslab + c * 512 + l * 8, As + c * 512);
            gload16(bslab + c * 512 + l * 8, Bs + c * 512);
        }
        __syncthreads();
#pragma unroll
        for (int s = 0; s < 2; ++s) {
            bf16x8 af[4], bfr[4];
#pragma unroll
            for (int m = 0; m < 4; ++m)
                af[m] = *(const bf16x8*)&As[(s * 4 + kg) * 1024 + (wr * 64 + m * 16 + li) * 8];
#pragma unroll
            for (int n = 0; n < 4; ++n)
                bfr[n] = *(const bf16x8*)&Bs[(s * 4 + kg) * 1024 + (wc * 64 + n * 16 + li) * 8];
#pragma unroll
            for (int m = 0; m < 4; ++m)
#pragma unroll
                for (int n = 0; n < 4; ++n)
                    acc[m][n] = __builtin_amdgcn_mfma_f32_16x16x32_bf16(af[m], bfr[n], acc[m][n], 0, 0, 0);
        }
        __syncthreads();
    }

    int jrow4 = (l >> 4) * 4;
    float bv[4];
#pragma unroll
    for (int n = 0; n < 4; ++n) bv[n] = bias[n0 + wc * 64 + n * 16 + li];
#pragma unroll
    for (int m = 0; m < 4; ++m)
#pragma unroll
        for (int j = 0; j < 4; ++j) {
            int i = m0 + wr * 64 + m * 16 + jrow4 + j;
            if (i >= nrows) continue;
#pragma unroll
            for (int n = 0; n < 4; ++n) {
                int col = n0 + wc * 64 + n * 16 + li;
                float val = fast_tanh(acc[m][n][j] + bv[n]);
                if (DUAL) {
                    if (i < B_ * NK_) {
                        int b = i / NK_, k = i - b * NK_;
                        long gr = (long)b * NN_ + NO_ + k;
                        node_tl[tiled_off((int)gr, col, 16)] = f2bf(val);
                    } else {
                        int i2 = i - B_ * NK_;
                        int b = i2 / KE_, k = i2 - b * KE_;
                        long gr = (long)b * NEK_ + NE_ + k;
                        edge_tl[tiled_off((int)gr, col, 16)] = f2bf(val);
                    }
                } else {
                    outf[(long)i * H_ + col] = val;
                }
            }
        }
}

// ---------------------------------------------------------------------------
// MFMA GEMM: 128x128 tile, BK=64 single-buffer, grid (panels, 4).
// AV: 3 = tiled A (contiguous slab copy), 2 = gathered img_f rows (K=1024).
// EP: 0 img_node, 1 img_edge (tiled out), 2 score partials.
template<int AV, int EP, int NCH>
__global__ __launch_bounds__(256) void mfma_gemm_kernel(
    const short* __restrict__ A, const short* __restrict__ Wp,
    const int* __restrict__ id1, const int* __restrict__ id2,
    const short* __restrict__ Agather,
    const float* __restrict__ bias, const float* __restrict__ bias2,
    const float* __restrict__ loc, const float* __restrict__ Wloc,
    const float* __restrict__ qp, const float* __restrict__ vvec,
    short* __restrict__ out0, short* __restrict__ out1,
    float* __restrict__ sout, int Nrows, int Mtot)
{
    __shared__ __align__(16) short As[8192];
    __shared__ __align__(16) short Bs[8192];
    int tid = threadIdx.x;
    int m0 = blockIdx.x * 128, nb = blockIdx.y, n0 = nb * 128;
    int w = tid >> 6, l = tid & 63, wr = w >> 1, wc = w & 1;

    int r1[2], r2[2];                          // AV=2 gathered rows (per lane)
    if (AV == 2) {
#pragma unroll
        for (int i = 0; i < 2; ++i) {
            int row = m0 + i * 64 + l;
            int b = row / NE_;
            r1[i] = b * NO_ + id1[row];
            r2[i] = b * NO_ + id2[row];
        }
    }
    const short* wslab = Wp + (long)nb * (NCH * 2) * 4096;
    const short* aslab0 = (AV == 3) ? A + (long)blockIdx.x * (NCH * 2) * 4096 : nullptr;

    f32x4 acc[4][4];
#pragma unroll
    for (int m = 0; m < 4; ++m)
#pragma unroll
        for (int n = 0; n < 4; ++n)
#pragma unroll
            for (int k = 0; k < 4; ++k) acc[m][n][k] = 0.f;

    int kg = l >> 4, li = l & 15;
    for (int t = 0; t < NCH; ++t) {
        const short* bslab = wslab + (long)(t * 2) * 4096;
#pragma unroll
        for (int j = 0; j < 4; ++j) {
            int c = w * 4 + j;
            if (AV == 3) {
                gload16(aslab0 + (long)(t * 2) * 4096 + c * 512 + l * 8, As + c * 512);
            } else {
                int g = c >> 1, h2 = c & 1;
                int kk = t * 64 + g * 8;
                int row = (kk < 512) ? r1[h2] : r2[h2];
                gload16(Agather + (long)row * 512 + (kk & 511), As + c * 512);
            }
            gload16(bslab + c * 512 + l * 8, Bs + c * 512);
        }
        __syncthreads();
#pragma unroll
        for (int s = 0; s < 2; ++s) {
            bf16x8 af[4], bfr[4];
#pragma unroll
            for (int m = 0; m < 4; ++m)
                af[m] = *(const bf16x8*)&As[(s * 4 + kg) * 1024 + (wr * 64 + m * 16 + li) * 8];
#pragma unroll
            for (int n = 0; n < 4; ++n)
                bfr[n] = *(const bf16x8*)&Bs[(s * 4 + kg) * 1024 + (wc * 64 + n * 16 + li) * 8];
#pragma unroll
            for (int m = 0; m < 4; ++m)
#pragma unroll
                for (int n = 0; n < 4; ++n)
                    acc[m][n] = __builtin_amdgcn_mfma_f32_16x16x32_bf16(af[m], bfr[n], acc[m][n], 0, 0, 0);
        }
        __syncthreads();
    }

    int jrow4 = (l >> 4) * 4;
    if (EP == 0) {                             // img_node
        float bi[4], bl[4], wl[4][5];
#pragma unroll
        for (int n = 0; n < 4; ++n) {
            int col = n0 + wc * 64 + n * 16 + li;
            bi[n] = bias[col]; bl[n] = bias2[col];
#pragma unroll
            for (int j5 = 0; j5 < 5; ++j5) wl[n][j5] = Wloc[j5 * H_ + col];
        }
#pragma unroll
        for (int m = 0; m < 4; ++m)
#pragma unroll
            for (int j = 0; j < 4; ++j) {
                int row = m0 + wr * 64 + m * 16 + jrow4 + j;
                int b = row / NO_, o = row - b * NO_;
                float lv[5];
#pragma unroll
                for (int j5 = 0; j5 < 5; ++j5) lv[j5] = loc[(long)row * 5 + j5];
                long gr = (long)b * NN_ + o;
#pragma unroll
                for (int n = 0; n < 4; ++n) {
                    int col = n0 + wc * 64 + n * 16 + li;
                    float val = acc[m][n][j] + bi[n];
                    out0[(long)row * H_ + col] = f2bf(val);          // img_f row-major
                    float nk = val + bl[n];
#pragma unroll
                    for (int j5 = 0; j5 < 5; ++j5) nk = fmaf(lv[j5], wl[n][j5], nk);
                    out1[tiled_off((int)gr, col, 16)] = f2bf(nk);    // node keys tiled
                }
            }
    } else if (EP == 1) {                      // img_edge
        float bi[4];
#pragma unroll
        for (int n = 0; n < 4; ++n) bi[n] = bias[n0 + wc * 64 + n * 16 + li];
#pragma unroll
        for (int m = 0; m < 4; ++m)
#pragma unroll
            for (int j = 0; j < 4; ++j) {
                int row = m0 + wr * 64 + m * 16 + jrow4 + j;
                int b = row / NE_, e = row - b * NE_;
                long gr = (long)b * NEK_ + e;
#pragma unroll
                for (int n = 0; n < 4; ++n) {
                    int col = n0 + wc * 64 + n * 16 + li;
                    out0[tiled_off((int)gr, col, 16)] = f2bf(acc[m][n][j] + bi[n]);
                }
            }
    } else {                                   // score partials
        float vv[4];
        int cols[4];
#pragma unroll
        for (int n = 0; n < 4; ++n) {
            cols[n] = n0 + wc * 64 + n * 16 + li;
            vv[n] = vvec[cols[n]];
        }
        int slot = nb * 2 + wc;
#pragma unroll
        for (int m = 0; m < 4; ++m)
#pragma unroll
            for (int j = 0; j < 4; ++j) {
                int row = m0 + wr * 64 + m * 16 + jrow4 + j;
                int b = row / Nrows;
                const float* qpb = qp + (long)b * H_;
                float p = 0.f;
#pragma unroll
                for (int n = 0; n < 4; ++n)
                    p += fast_tanh(qpb[cols[n]] + acc[m][n][j]) * vv[n];
                p += __shfl_xor(p, 1); p += __shfl_xor(p, 2);
                p += __shfl_xor(p, 4); p += __shfl_xor(p, 8);
                if (li == 0) sout[(long)slot * Mtot + row] = p;
            }
    }
}

// ---------------------------------------------------------------------------
// Softmax weights: combine 8 deterministic partials, mask, normalize.
__global__ __launch_bounds__(256) void softmax_w_kernel(
    const float* __restrict__ sp_n, const float* __restrict__ sp_e,
    const float* __restrict__ maskbuf, float* __restrict__ wn, float* __restrict__ we)
{
    __shared__ float sw[NEK_];
    __shared__ float red[256];
    int b = blockIdx.x, tid = threadIdx.x, set = blockIdx.y;
    const float* sp = set ? sp_e : sp_n;
    float* wout = set ? we : wn;
    int N = set ? NEK_ : NN_;
    long Mtot = set ? (long)B_ * NEK_ : (long)B_ * NN_;

    float lmax = -3.0e38f;
    for (int n = tid; n < N; n += 256) {
        long row = (long)b * N + n;
        float x = 0.f;
#pragma unroll
        for (int s = 0; s < 8; ++s) x += sp[(long)s * Mtot + row];
        if (!set && n >= NO_ && maskbuf[(long)b * NK_ + (n - NO_)] == 0.f) x = -1e30f;
        sw[n] = x;
        lmax = fmaxf(lmax, x);
    }
    red[tid] = lmax; __syncthreads();
    for (int st = 128; st > 0; st >>= 1) {
        if (tid < st) red[tid] = fmaxf(red[tid], red[tid + st]);
        __syncthreads();
    }
    float mx = red[0]; __syncthreads();

    float lsum = 0.f;
    for (int n = tid; n < N; n += 256) {
        float e = expf(sw[n] - mx);
        sw[n] = e;
        lsum += e;
    }
    red[tid] = lsum; __syncthreads();
    for (int st = 128; st > 0; st >>= 1) {
        if (tid < st) red[tid] += red[tid + st];
        __syncthreads();
    }
    float invZ = 1.0f / red[0];
    __syncthreads();
    for (int n = tid; n < N; n += 256)
        wout[(long)b * N + n] = sw[n] * invZ;
}

// ---------------------------------------------------------------------------
// Weighted key sum over TILED keys, split over n: grid (B, SP).
template<int SP>
__global__ __launch_bounds__(256) void wsum_kernel(
    const float* __restrict__ w, const short* __restrict__ keys_tl,
    float* __restrict__ partial, int N)
{
    __shared__ float red[4][512];
    int b = blockIdx.x, sp = blockIdx.y, tid = threadIdx.x;
    int c8 = (tid & 63) * 8, rsub = tid >> 6;
    int per = (N + SP - 1) / SP;
    int n0 = sp * per, n1 = min(n0 + per, N);
    float acc[8] = {0.f,0.f,0.f,0.f,0.f,0.f,0.f,0.f};
    for (int n = n0 + rsub; n < n1; n += 4) {
        float wv = w[(long)b * N + n];
        bf16x8 k = *(const bf16x8*)&keys_tl[tiled_off(b * N + n, c8, 16)];
#pragma unroll
        for (int j = 0; j < 8; ++j) acc[j] = fmaf(wv, bf2f(k[j]), acc[j]);
    }
    *(float4*)&red[rsub][c8]     = *(float4*)acc;
    *(float4*)&red[rsub][c8 + 4] = *(float4*)(acc + 4);
    __syncthreads();
    if (rsub == 0) {
        float o[8];
#pragma unroll
        for (int j = 0; j < 8; ++j)
            o[j] = red[0][c8 + j] + red[1][c8 + j] + red[2][c8 + j] + red[3][c8 + j];
        float* op = &partial[((long)sp * B_ + b) * H_ + c8];
        *(float4*)op       = *(float4*)o;
        *(float4*)(op + 4) = *(float4*)(o + 4);
    }
}

// fin = sum over 16 node partials + 16 edge partials. grid (B*H/256).
__global__ __launch_bounds__(256) void fin_reduce_kernel(
    const float* __restrict__ pn, const float* __restrict__ pe, float* __restrict__ fin)
{
    int i = blockIdx.x * 256 + threadIdx.x;
    float s = 0.f;
#pragma unroll
    for (int sp = 0; sp < 16; ++sp)
        s += pn[(long)sp * B_ * H_ + i] + pe[(long)sp * B_ * H_ + i];
    fin[i] = s;
}

// ---------------------------------------------------------------------------
// K-split matvec over all 32 batch rows; deterministic partials.
template<int E, int CHUNK>
__global__ __launch_bounds__(256) void kmatvec_kernel(
    const float* __restrict__ in, const float* __restrict__ Wa,
    const float* __restrict__ Wb, float* __restrict__ pa,
    float* __restrict__ pb, int C)
{
    __shared__ float ins[32 * CHUNK];
    int tid = threadIdx.x;
    int ks = blockIdx.y, k0 = ks * CHUNK;
    const float* W   = (blockIdx.z == 0) ? Wa : Wb;
    float* partial   = (blockIdx.z == 0) ? pa : pb;
    for (int t = tid; t < 32 * CHUNK; t += 256) {
        int b = t / CHUNK, k = t - b * CHUNK;
        ins[t] = in[(long)b * E + k0 + k];
    }
    __syncthreads();
    int c = blockIdx.x * 256 + tid;
    if (c >= C) return;
    float acc[32];
#pragma unroll
    for (int b = 0; b < 32; ++b) acc[b] = 0.f;
    for (int k = 0; k < CHUNK; ++k) {
        float wv = W[(long)(k0 + k) * C + c];
#pragma unroll
        for (int b = 0; b < 32; ++b)
            acc[b] = fmaf(ins[b * CHUNK + k], wv, acc[b]);
    }
#pragma unroll
    for (int b = 0; b < 32; ++b)
        partial[((long)ks * 32 + b) * C + c] = acc[b];
}

template<int ACT, int KS>
__global__ __launch_bounds__(256) void kreduce_kernel(
    const float* __restrict__ pa, const float* __restrict__ pb,
    const float* __restrict__ biasa, const float* __restrict__ biasb,
    float* __restrict__ oa, float* __restrict__ ob, int C)
{
    int set = blockIdx.y;
    const float* p    = set ? pb : pa;
    const float* bias = set ? biasb : biasa;
    float* o          = set ? ob : oa;
    long i = (long)blockIdx.x * 256 + threadIdx.x;
    if (i >= 32L * C) return;
    int c = (int)(i % C);
    float s = bias ? bias[c] : 0.f;
#pragma unroll
    for (int ks = 0; ks < KS; ++ks) s += p[(long)ks * 32 * C + i];
    o[i] = (ACT == 1) ? fast_tanh(s) : s;
}

// ---------------------------------------------------------------------------
extern "C" void kernel_launch(void* const* d_in, const int* in_sizes, int n_in,
                              void* d_out, int out_size, void* d_ws, size_t ws_size,
                              hipStream_t stream)
{
    (void)in_sizes; (void)n_in; (void)out_size; (void)ws_size;

    const float* img_feat  = (const float*)d_in[0];
    const float* img_loc   = (const float*)d_in[1];
    const int*   id1       = (const int*)d_in[2];
    const int*   id2       = (const int*)d_in[3];
    const int*   kg_entity = (const int*)d_in[4];
    const int*   kg_edge   = (const int*)d_in[7];
    const int*   r_nodes   = (const int*)d_in[8];
    const float* embed     = (const float*)d_in[11];
    const float* W_lang    = (const float*)d_in[12];
    const float* b_lang    = (const float*)d_in[13];
    const float* W_img     = (const float*)d_in[14];
    const float* b_img     = (const float*)d_in[15];
    const float* W_loc     = (const float*)d_in[16];
    const float* b_loc     = (const float*)d_in[17];
    const float* W_rel     = (const float*)d_in[18];
    const float* b_rel     = (const float*)d_in[19];
    const float* Wq_n      = (const float*)d_in[20];
    const float* Wk_n      = (const float*)d_in[21];
    const float* v_n       = (const float*)d_in[22];
    const float* Wq_e      = (const float*)d_in[23];
    const float* Wk_e      = (const float*)d_in[24];
    const float* v_e       = (const float*)d_in[25];
    const float* W1        = (const float*)d_in[26];
    const float* b1        = (const float*)d_in[27];
    const float* W2        = (const float*)d_in[28];
    const float* b2        = (const float*)d_in[29];
    float* out = (float*)d_out;

    char* ws = (char*)d_ws;
    size_t off = 0;
    auto allocS = [&](size_t n) { short* p = (short*)(ws + off); off += ((n * 2 + 255) & ~255ULL); return p; };
    auto allocF = [&](size_t n) { float* p = (float*)(ws + off); off += ((n * 4 + 255) & ~255ULL); return p; };

    short* img_feat_tl = allocS((size_t)B_ * NO_ * IMG_);      // 13 MB (tiled)
    short* embed_bf    = allocS((size_t)10000 * EMB_ + 16);    // 6 MB
    short* Wp_img      = allocS((size_t)4 * 64 * 4096);
    short* Wp_rel      = allocS((size_t)4 * 32 * 4096);
    short* Wp_kn       = allocS((size_t)4 * 16 * 4096);
    short* Wp_ke       = allocS((size_t)4 * 16 * 4096);
    short* Wp_lang     = allocS((size_t)4 * 10 * 4096);
    short* img_f_bf    = allocS((size_t)B_ * NO_ * H_);        // row-major (gather src)
    short* node_tl     = allocS((size_t)B_ * NN_ * H_);        // 36 MB tiled keys
    short* edge_tl     = allocS((size_t)B_ * NEK_ * H_);       // 52 MB tiled keys
    short* pooled      = allocS((size_t)2 * B_ * NK_ * 320);   // 41 MB tiled
    short* pooled_r    = allocS((size_t)10 * 4096);            // 1 panel tiled
    float* rfeat   = allocF((size_t)B_ * H_);
    float* qp_n    = allocF((size_t)B_ * H_);
    float* qp_e    = allocF((size_t)B_ * H_);
    float* mask_kg = allocF((size_t)B_ * NK_);
    float* sp_n    = allocF((size_t)8 * B_ * NN_);             // score partials
    float* sp_e    = allocF((size_t)8 * B_ * NEK_);
    float* wn      = allocF((size_t)B_ * NN_);
    float* we      = allocF((size_t)B_ * NEK_);
    float* pn      = allocF((size_t)16 * B_ * H_);
    float* pe      = allocF((size_t)16 * B_ * H_);
    float* fin     = allocF((size_t)B_ * H_);
    float* hid     = allocF((size_t)B_ * H_);
    float* pq_n    = allocF((size_t)16 * B_ * MID_);
    float* pq_e    = allocF((size_t)16 * B_ * MID_);
    float* ph1     = allocF((size_t)16 * B_ * MID_);
    float* ph2     = allocF((size_t)16 * B_ * C_);

    // --- weight prep + input conversion ---
    cvt_tiled_kernel<<<(B_ * NO_ * IMG_ / 8 + 255) / 256, 256, 0, stream>>>(
        img_feat, img_feat_tl, IMG_, (long)B_ * NO_ * IMG_ / 8);
    cvt_bf16_kernel<<<(10000 * EMB_ / 8 + 255) / 256, 256, 0, stream>>>(
        embed, embed_bf, (long)10000 * EMB_);
    wprep_kernel<<<512, 256, 0, stream>>>(W_img,  Wp_img,  IMG_, 64);
    wprep_kernel<<<256, 256, 0, stream>>>(W_rel,  Wp_rel,  1024, 32);
    wprep_kernel<<<128, 256, 0, stream>>>(Wk_n,   Wp_kn,   512,  16);
    wprep_kernel<<<128, 256, 0, stream>>>(Wk_e,   Wp_ke,   512,  16);
    wprep_kernel<<< 80, 256, 0, stream>>>(W_lang, Wp_lang, EMB_, 10);

    // --- pooled embeddings (merged node+edge gather, tiled out) ---
    pool_kernel<<<2 * B_ * NK_ / 32, 256, 0, stream>>>(
        kg_entity, kg_edge, B_ * NK_, L_, 0, embed_bf, pooled, mask_kg, 2 * B_ * NK_);
    pool_kernel<<<1, 256, 0, stream>>>(
        r_nodes, nullptr, 1 << 30, R_ * L_, (R_ - 1) * L_, embed_bf, pooled_r,
        nullptr, B_);

    // --- lang projections (A = tiled slabs; keys written tiled) ---
    keys_gemm_kernel<1><<<dim3(2 * B_ * NK_ / 128, 4), 256, 0, stream>>>(
        pooled, Wp_lang, b_lang, node_tl, edge_tl, nullptr, 2 * B_ * NK_);
    keys_gemm_kernel<0><<<dim3(1, 4), 256, 0, stream>>>(
        pooled_r, Wp_lang, b_lang, nullptr, nullptr, rfeat, B_);

    // --- qp for root program node (fused pair, K-split) ---
    kmatvec_kernel<H_, 32><<<dim3(2, 16, 2), 256, 0, stream>>>(
        rfeat, Wq_n, Wq_e, pq_n, pq_e, MID_);
    kreduce_kernel<0, 16><<<dim3(B_ * MID_ / 256, 2), 256, 0, stream>>>(
        pq_n, pq_e, nullptr, nullptr, qp_n, qp_e, MID_);

    // --- image branches ---
    mfma_gemm_kernel<3, 0, 32><<<dim3(B_ * NO_ / 128, 4), 256, 0, stream>>>(
        img_feat_tl, Wp_img, nullptr, nullptr, nullptr,
        b_img, b_loc, img_loc, W_loc, nullptr, nullptr,
        img_f_bf, node_tl, nullptr, 0, 0);
    mfma_gemm_kernel<2, 1, 16><<<dim3(B_ * NE_ / 128, 4), 256, 0, stream>>>(
        nullptr, Wp_rel, id1, id2, img_f_bf,
        b_rel, nullptr, nullptr, nullptr, nullptr, nullptr,
        edge_tl, nullptr, nullptr, 0, 0);

    // --- fused keys@Wk + tanh-attention score partials (A tiled) ---
    mfma_gemm_kernel<3, 2, 8><<<dim3(B_ * NN_ / 128, 4), 256, 0, stream>>>(
        node_tl, Wp_kn, nullptr, nullptr, nullptr,
        nullptr, nullptr, nullptr, nullptr, qp_n, v_n,
        nullptr, nullptr, sp_n, NN_, B_ * NN_);
    mfma_gemm_kernel<3, 2, 8><<<dim3(B_ * NEK_ / 128, 4), 256, 0, stream>>>(
        edge_tl, Wp_ke, nullptr, nullptr, nullptr,
        nullptr, nullptr, nullptr, nullptr, qp_e, v_e,
        nullptr, nullptr, sp_e, NEK_, B_ * NEK_);

    // --- softmax weights + parallel weighted sums (tiled keys) ---
    softmax_w_kernel<<<dim3(B_, 2), 256, 0, stream>>>(sp_n, sp_e, mask_kg, wn, we);
    wsum_kernel<16><<<dim3(B_, 16), 256, 0, stream>>>(wn, node_tl, pn, NN_);
    wsum_kernel<16><<<dim3(B_, 16), 256, 0, stream>>>(we, edge_tl, pe, NEK_);
    fin_reduce_kernel<<<B_ * H_ / 256, 256, 0, stream>>>(pn, pe, fin);

    // --- head: hid = tanh(fin@W1 + b1); out = hid@W2 + b2 ---
    kmatvec_kernel<H_, 32><<<dim3(2, 16, 1), 256, 0, stream>>>(
        fin, W1, W1, ph1, ph1, MID_);
    kreduce_kernel<1, 16><<<dim3(B_ * MID_ / 256, 1), 256, 0, stream>>>(
        ph1, ph1, b1, b1, hid, hid, MID_);
    kmatvec_kernel<MID_, 32><<<dim3((C_ + 255) / 256, 16, 1), 256, 0, stream>>>(
        hid, W2, W2, ph2, ph2, C_);
    kreduce_kernel<0, 16><<<dim3((B_ * C_ + 255) / 256, 1), 256, 0, stream>>>(
        ph2, ph2, b2, b2, out, out, C_);
}